// Round 2
// baseline (5123.056 us; speedup 1.0000x reference)
//
#include <hip/hip_runtime.h>
#include <hip/hip_bf16.h>

#define NN 100000
#define EE 3200000
#define FF 128
#define F2 256
#define VV 8
#define LL 3
#define EPSV 1e-5f

static inline int idiv(int a, int b){ return (a + b - 1) / b; }

// ---------- degree / dinv ----------
__global__ void k_deg_init(float* __restrict__ deg){
  int i = blockIdx.x * 256 + threadIdx.x;
  if (i < NN) deg[i] = 1.0f;   // self loop
}

__global__ void k_deg_edge(const int* __restrict__ dst, float* __restrict__ deg){
  int stride = gridDim.x * 256;
  for (int e = blockIdx.x * 256 + threadIdx.x; e < EE; e += stride)
    atomicAdd(&deg[dst[e]], 1.0f);
}

__global__ void k_dinv(const float* __restrict__ deg, float* __restrict__ dinv){
  int i = blockIdx.x * 256 + threadIdx.x;
  if (i < NN) dinv[i] = rsqrtf(deg[i]);
}

// ---------- per-edge weight w[e] = dinv[src]*dinv[dst] ----------
__global__ void k_edgew(const int* __restrict__ src, const int* __restrict__ dst,
                        const float* __restrict__ dinv, float* __restrict__ w){
  int stride = gridDim.x * 256;
  for (int e = blockIdx.x * 256 + threadIdx.x; e < EE; e += stride)
    w[e] = dinv[src[e]] * dinv[dst[e]];
}

// ---------- mask dtype detect: 1 = bool(1B), 0 = int32 ----------
__global__ void k_maskdetect(const unsigned char* __restrict__ m, int* __restrict__ flag){
  int any = 0;
  for (int t = threadIdx.x; t < 4096; t += 256)
    if ((t & 3) && m[t]) any = 1;
  if (any) atomicOr(flag, 1);
}

// ---------- rowvec = (sum_v vn[v]) @ W ----------
__global__ void k_vnrow(const float* __restrict__ vn, const float* __restrict__ W,
                        float* __restrict__ rowvec){
  __shared__ float vs[FF];
  int j = threadIdx.x;       // 128 threads
  float s = 0.f;
  for (int v = 0; v < VV; ++v) s += vn[v * FF + j];
  vs[j] = s;
  __syncthreads();
  float acc = 0.f;
  for (int k = 0; k < FF; ++k) acc += vs[k] * W[k * FF + j];
  rowvec[j] = acc;
}

// ---------- hl[n] = emb[n]@W + rowvec  (literal, no dinv folding) ----------
__launch_bounds__(256)
__global__ void k_matmul(const float* __restrict__ in, const float* __restrict__ W,
                         const float* __restrict__ rowvec, float* __restrict__ hl){
  __shared__ float Ws[FF * FF];     // 64 KB
  __shared__ float As[8 * FF];      // 4 KB
  __shared__ float rv[FF];
  int tid = threadIdx.x;
  for (int t = tid; t < FF * FF; t += 256) Ws[t] = W[t];
  if (tid < FF) rv[tid] = rowvec[tid];
  __syncthreads();
  int row = tid >> 5;               // 0..7
  int col = (tid & 31) * 4;         // 0..124
  float4 rvv = *(const float4*)&rv[col];
  for (int base = blockIdx.x * 8; base < NN; base += gridDim.x * 8){
    for (int t = tid; t < 8 * FF; t += 256)
      As[t] = in[(base + (t >> 7)) * FF + (t & 127)];
    __syncthreads();
    float4 acc = rvv;
    #pragma unroll 8
    for (int k = 0; k < FF; ++k){
      float a = As[row * FF + k];
      float4 wv = *(const float4*)&Ws[k * FF + col];
      acc.x += a * wv.x; acc.y += a * wv.y; acc.z += a * wv.z; acc.w += a * wv.w;
    }
    *(float4*)&hl[(base + row) * FF + col] = acc;
    __syncthreads();
  }
}

// ---------- agg[n] = hl[n] * dinv[n]^2  (self-loop term, full overwrite) ----------
__global__ void k_selfinit(const float* __restrict__ hl, const float* __restrict__ dinv,
                           float* __restrict__ agg){
  int stride = gridDim.x * 256;
  for (int i = blockIdx.x * 256 + threadIdx.x; i < NN * FF; i += stride){
    int r = i >> 7;
    float dv = dinv[r];
    agg[i] = hl[i] * dv * dv;
  }
}

// ---------- agg[dst] += w[e] * hl[src] ----------
__global__ void k_edge(const int* __restrict__ src, const int* __restrict__ dst,
                       const float* __restrict__ w, const float* __restrict__ hl,
                       float* __restrict__ agg){
  unsigned int total = (unsigned int)EE * FF;   // 409.6M
  unsigned int stride = gridDim.x * 256;
  for (unsigned int idx = blockIdx.x * 256 + threadIdx.x; idx < total; idx += stride){
    int e = (int)(idx >> 7);
    int f = (int)(idx & 127);
    atomicAdd(&agg[dst[e] * FF + f], w[e] * hl[src[e] * FF + f]);
  }
}

// ---------- add bias, accumulate BN column stats ----------
__global__ void k_finstats(float* __restrict__ agg, const float* __restrict__ bc,
                           float* __restrict__ stats){
  int tid = blockIdx.x * 256 + threadIdx.x;
  int j = tid & 127;
  int r = tid >> 7;
  int rs = (gridDim.x * 256) >> 7;
  float b = bc[j];
  float s = 0.f, sq = 0.f;
  for (; r < NN; r += rs){
    float v = agg[r * FF + j] + b;
    agg[r * FF + j] = v;
    s += v; sq += v * v;
  }
  atomicAdd(&stats[j], s);
  atomicAdd(&stats[FF + j], sq);
}

__global__ void k_bnfin(const float* __restrict__ stats, const float* __restrict__ g,
                        const float* __restrict__ b, float* __restrict__ ss){
  int j = threadIdx.x;   // 128
  float mean = stats[j] * (1.0f / NN);
  float var  = stats[FF + j] * (1.0f / NN) - mean * mean;
  float sc = rsqrtf(var + EPSV) * g[j];
  ss[j] = sc;
  ss[FF + j] = b[j] - mean * sc;
}

__global__ void k_bnapply(float4* __restrict__ h, const float* __restrict__ ss, int relu){
  int n4 = NN * FF / 4;
  int stride = gridDim.x * 256;
  for (int i = blockIdx.x * 256 + threadIdx.x; i < n4; i += stride){
    int c = (i & 31) * 4;
    float4 v = h[i];
    float4 sc = *(const float4*)&ss[c];
    float4 sh = *(const float4*)&ss[FF + c];
    v.x = v.x * sc.x + sh.x;
    v.y = v.y * sc.y + sh.y;
    v.z = v.z * sc.z + sh.z;
    v.w = v.w * sc.w + sh.w;
    if (relu){
      v.x = fmaxf(v.x, 0.f); v.y = fmaxf(v.y, 0.f);
      v.z = fmaxf(v.z, 0.f); v.w = fmaxf(v.w, 0.f);
    }
    h[i] = v;
  }
}

// ---------- pooled[v] = sum_{n: mask[v][n]} emb[n]  (mask dtype-adaptive) ----------
__global__ void k_pool(const float* __restrict__ emb, const unsigned char* __restrict__ m8,
                       const int* __restrict__ m32, const int* __restrict__ flag,
                       float* __restrict__ pooled){
  int isb = *flag;
  int tid = blockIdx.x * 256 + threadIdx.x;
  int j = tid & 127;
  int r = tid >> 7;
  int rs = (gridDim.x * 256) >> 7;
  float acc[VV];
  #pragma unroll
  for (int v = 0; v < VV; ++v) acc[v] = 0.f;
  for (; r < NN; r += rs){
    float xv = emb[r * FF + j];
    #pragma unroll
    for (int v = 0; v < VV; ++v){
      int mv = isb ? (int)m8[v * NN + r] : m32[v * NN + r];
      if (mv) acc[v] += xv;
    }
  }
  #pragma unroll
  for (int v = 0; v < VV; ++v) atomicAdd(&pooled[v * FF + j], acc[v]);
}

// ---------- per-VN MLP: F -> 2F (relu, LN) -> F (relu, LN) ----------
__device__ __forceinline__ float blockSum(float x, float* red, int tid){
  red[tid] = x; __syncthreads();
  #pragma unroll
  for (int s = 128; s >= 1; s >>= 1){
    if (tid < s) red[tid] += red[tid + s];
    __syncthreads();
  }
  float r = red[0];
  __syncthreads();
  return r;
}

__launch_bounds__(256)
__global__ void k_vnmlp(const float* __restrict__ pooled, const float* __restrict__ vnin,
                        const float* __restrict__ W1, const float* __restrict__ b1,
                        const float* __restrict__ g1, const float* __restrict__ bb1,
                        const float* __restrict__ W2, const float* __restrict__ b2,
                        const float* __restrict__ g2, const float* __restrict__ bb2,
                        float* __restrict__ vnout){
  int v = blockIdx.x;
  int tid = threadIdx.x;
  __shared__ float tmp_s[FF];
  __shared__ float h1_s[F2];
  __shared__ float red[256];
  if (tid < FF) tmp_s[tid] = pooled[v * FF + tid] + vnin[v * FF + tid];
  __syncthreads();
  const float* W1v = W1 + (size_t)v * FF * F2;
  float acc = b1[v * F2 + tid];
  for (int k = 0; k < FF; ++k) acc += tmp_s[k] * W1v[k * F2 + tid];
  acc = fmaxf(acc, 0.f);
  float sum = blockSum(acc, red, tid);
  float sq  = blockSum(acc * acc, red, tid);
  float mean = sum * (1.f / F2);
  float var  = sq * (1.f / F2) - mean * mean;
  float y = (acc - mean) * rsqrtf(var + EPSV) * g1[v * F2 + tid] + bb1[v * F2 + tid];
  h1_s[tid] = y;
  __syncthreads();
  const float* W2v = W2 + (size_t)v * F2 * FF;
  float h2 = 0.f;
  if (tid < FF){
    float a2 = b2[v * FF + tid];
    for (int k = 0; k < F2; ++k) a2 += h1_s[k] * W2v[k * FF + tid];
    h2 = fmaxf(a2, 0.f);
  }
  float sum2 = blockSum((tid < FF) ? h2 : 0.f, red, tid);
  float sq2  = blockSum((tid < FF) ? h2 * h2 : 0.f, red, tid);
  float mean2 = sum2 * (1.f / FF);
  float var2  = sq2 * (1.f / FF) - mean2 * mean2;
  if (tid < FF)
    vnout[v * FF + tid] = (h2 - mean2) * rsqrtf(var2 + EPSV) * g2[v * FF + tid]
                          + bb2[v * FF + tid];
}

extern "C" void kernel_launch(void* const* d_in, const int* in_sizes, int n_in,
                              void* d_out, int out_size, void* d_ws, size_t ws_size,
                              hipStream_t stream){
  const float* x        = (const float*)d_in[0];
  const int*   ei       = (const int*)d_in[1];
  const unsigned char* vmask8 = (const unsigned char*)d_in[2];
  const int*   vmask32  = (const int*)d_in[2];
  const float* Wc       = (const float*)d_in[3];
  const float* bc       = (const float*)d_in[4];
  const float* bn_g     = (const float*)d_in[5];
  const float* bn_b     = (const float*)d_in[6];
  const float* vn_embed = (const float*)d_in[7];
  const float* mlp_W1   = (const float*)d_in[8];
  const float* mlp_b1   = (const float*)d_in[9];
  const float* ln1_g    = (const float*)d_in[10];
  const float* ln1_b    = (const float*)d_in[11];
  const float* mlp_W2   = (const float*)d_in[12];
  const float* mlp_b2   = (const float*)d_in[13];
  const float* ln2_g    = (const float*)d_in[14];
  const float* ln2_b    = (const float*)d_in[15];
  float* out = (float*)d_out;

  float* bufA   = (float*)d_ws;                    // N*F   (hl)
  float* bufB   = bufA + (size_t)NN * FF;          // N*F   (agg layer 0)
  float* ew     = bufB + (size_t)NN * FF;          // E     (edge weights)
  float* deg    = ew + EE;                         // N
  float* dinv   = deg + NN;                        // N
  float* stats  = dinv + NN;                       // 4F (sums | scale/shift)
  float* rowvec = stats + 4 * FF;                  // F
  float* pooled = rowvec + FF;                     // V*F
  float* vnA    = pooled + VV * FF;                // V*F
  float* vnB    = vnA + VV * FF;                   // V*F
  int*   mflag  = (int*)(vnB + VV * FF);           // 1

  const int* esrc = ei;
  const int* edst = ei + EE;

  k_deg_init<<<idiv(NN, 256), 256, 0, stream>>>(deg);
  k_deg_edge<<<1024, 256, 0, stream>>>(edst, deg);
  k_dinv<<<idiv(NN, 256), 256, 0, stream>>>(deg, dinv);
  k_edgew<<<1024, 256, 0, stream>>>(esrc, edst, dinv, ew);
  hipMemsetAsync(mflag, 0, sizeof(int), stream);
  k_maskdetect<<<1, 256, 0, stream>>>(vmask8, mflag);

  const float* vncur = vn_embed;
  const float* embin = x;
  float* vnbufs[2] = {vnA, vnB};

  for (int l = 0; l < LL; ++l){
    float* hl  = bufA;
    float* agg = (l == 0) ? bufB : out;   // l=1: out; l=2: out (embin==out safe: selfinit after matmul)
    const float* Wl = Wc + (size_t)l * FF * FF;

    k_vnrow<<<1, 128, 0, stream>>>(vncur, Wl, rowvec);
    k_matmul<<<2048, 256, 0, stream>>>(embin, Wl, rowvec, hl);

    if (l < LL - 1){
      hipMemsetAsync(pooled, 0, VV * FF * sizeof(float), stream);
      k_pool<<<1024, 256, 0, stream>>>(embin, vmask8, vmask32, mflag, pooled);
    }

    k_selfinit<<<2048, 256, 0, stream>>>(hl, dinv, agg);
    k_edge<<<8192, 256, 0, stream>>>(esrc, edst, ew, hl, agg);

    hipMemsetAsync(stats, 0, 2 * FF * sizeof(float), stream);
    k_finstats<<<2048, 256, 0, stream>>>(agg, bc + l * FF, stats);
    k_bnfin<<<1, 128, 0, stream>>>(stats, bn_g + l * FF, bn_b + l * FF, stats + 2 * FF);
    k_bnapply<<<2048, 256, 0, stream>>>((float4*)agg, stats + 2 * FF, (l < LL - 1) ? 1 : 0);

    if (l < LL - 1){
      k_vnmlp<<<VV, 256, 0, stream>>>(pooled, vncur,
          mlp_W1 + (size_t)l * VV * FF * F2, mlp_b1 + (size_t)l * VV * F2,
          ln1_g + (size_t)l * VV * F2, ln1_b + (size_t)l * VV * F2,
          mlp_W2 + (size_t)l * VV * F2 * FF, mlp_b2 + (size_t)l * VV * FF,
          ln2_g + (size_t)l * VV * FF, ln2_b + (size_t)l * VV * FF,
          vnbufs[l]);
      vncur = vnbufs[l];
      embin = agg;
    }
  }
}

// Round 3
// 2330.730 us; speedup vs baseline: 2.1980x; 2.1980x over previous
//
#include <hip/hip_runtime.h>
#include <hip/hip_bf16.h>

#define NN 100000
#define EE 3200000
#define FF 128
#define F2 256
#define VV 8
#define LL 3
#define EPSV 1e-5f
#define NB 98   // idiv(NN,1024)

static inline int idiv(int a, int b){ return (a + b - 1) / b; }

// ---------- in-degree (without self loop) ----------
__global__ void k_edeg_zero(int* __restrict__ edeg){
  int i = blockIdx.x * 256 + threadIdx.x;
  if (i < NN) edeg[i] = 0;
}

__global__ void k_deg(const int* __restrict__ dst, int* __restrict__ edeg){
  int stride = gridDim.x * 256;
  for (int e = blockIdx.x * 256 + threadIdx.x; e < EE; e += stride)
    atomicAdd(&edeg[dst[e]], 1);
}

__global__ void k_dinv(const int* __restrict__ edeg, float* __restrict__ dinv){
  int i = blockIdx.x * 256 + threadIdx.x;
  if (i < NN) dinv[i] = rsqrtf((float)(edeg[i] + 1));
}

// ---------- exclusive scan of edeg -> offs ----------
__global__ void k_scanA(const int* __restrict__ edeg, int* __restrict__ offs,
                        int* __restrict__ bsum){
  __shared__ int s[1024];
  int t = threadIdx.x;
  int i = blockIdx.x * 1024 + t;
  int v = (i < NN) ? edeg[i] : 0;
  int x = v;
  s[t] = x; __syncthreads();
  for (int d = 1; d < 1024; d <<= 1){
    int y = (t >= d) ? s[t - d] : 0;
    __syncthreads();
    x += y; s[t] = x;
    __syncthreads();
  }
  if (i < NN) offs[i] = x - v;
  if (t == 1023) bsum[blockIdx.x] = x;
}

__global__ void k_scanB(int* __restrict__ bsum){
  __shared__ int s[128];
  int t = threadIdx.x;
  s[t] = (t < NB) ? bsum[t] : 0;
  __syncthreads();
  if (t == 0){
    int run = 0;
    for (int k = 0; k < NB; ++k){ int tmp = s[k]; s[k] = run; run += tmp; }
  }
  __syncthreads();
  if (t < NB) bsum[t] = s[t];
}

__global__ void k_scanC(int* __restrict__ offs, const int* __restrict__ bsum,
                        int* __restrict__ cursor){
  int i = blockIdx.x * 256 + threadIdx.x;
  if (i < NN){
    int o = offs[i] + bsum[i >> 10];
    offs[i] = o;
    cursor[i] = o;
  }
  if (i == 0) offs[NN] = EE;
}

// ---------- counting-sort scatter: ssorted = src ids grouped by dst ----------
__global__ void k_scatter(const int* __restrict__ src, const int* __restrict__ dst,
                          int* __restrict__ cursor, int* __restrict__ ssorted){
  int stride = gridDim.x * 256;
  for (int e = blockIdx.x * 256 + threadIdx.x; e < EE; e += stride){
    int d = dst[e];
    int pos = atomicAdd(&cursor[d], 1);
    ssorted[pos] = src[e];
  }
}

// ---------- mask dtype detect: 1 = bool(1B), 0 = int32 ----------
__global__ void k_maskdetect(const unsigned char* __restrict__ m, int* __restrict__ flag){
  int any = 0;
  for (int t = threadIdx.x; t < 4096; t += 256)
    if ((t & 3) && m[t]) any = 1;
  if (any) atomicOr(flag, 1);
}

// ---------- rowvec = (sum_v vn[v]) @ W ----------
__global__ void k_vnrow(const float* __restrict__ vn, const float* __restrict__ W,
                        float* __restrict__ rowvec){
  __shared__ float vs[FF];
  int j = threadIdx.x;       // 128 threads
  float s = 0.f;
  for (int v = 0; v < VV; ++v) s += vn[v * FF + j];
  vs[j] = s;
  __syncthreads();
  float acc = 0.f;
  for (int k = 0; k < FF; ++k) acc += vs[k] * W[k * FF + j];
  rowvec[j] = acc;
}

// ---------- hl[n] = emb[n]@W + rowvec ----------
__launch_bounds__(256)
__global__ void k_matmul(const float* __restrict__ in, const float* __restrict__ W,
                         const float* __restrict__ rowvec, float* __restrict__ hl){
  __shared__ float Ws[FF * FF];     // 64 KB
  __shared__ float As[8 * FF];      // 4 KB
  __shared__ float rv[FF];
  int tid = threadIdx.x;
  for (int t = tid; t < FF * FF; t += 256) Ws[t] = W[t];
  if (tid < FF) rv[tid] = rowvec[tid];
  __syncthreads();
  int row = tid >> 5;               // 0..7
  int col = (tid & 31) * 4;         // 0..124
  float4 rvv = *(const float4*)&rv[col];
  for (int base = blockIdx.x * 8; base < NN; base += gridDim.x * 8){
    for (int t = tid; t < 8 * FF; t += 256)
      As[t] = in[(base + (t >> 7)) * FF + (t & 127)];
    __syncthreads();
    float4 acc = rvv;
    #pragma unroll 8
    for (int k = 0; k < FF; ++k){
      float a = As[row * FF + k];
      float4 wv = *(const float4*)&Ws[k * FF + col];
      acc.x += a * wv.x; acc.y += a * wv.y; acc.z += a * wv.z; acc.w += a * wv.w;
    }
    *(float4*)&hl[(base + row) * FF + col] = acc;
    __syncthreads();
  }
}

// ---------- CSR gather: agg[n] = dinv[n]*(sum_e dinv[s]*hl[s]) + dinv[n]^2*hl[n] + b
//            fused with BN column-stat accumulation ----------
__launch_bounds__(256)
__global__ void k_gather(const float4* __restrict__ hl4, const float* __restrict__ dinv,
                         const int* __restrict__ offs, const int* __restrict__ ssorted,
                         const float* __restrict__ bias, float4* __restrict__ agg4,
                         float* __restrict__ stats){
  __shared__ float4 red[256];
  int tid = threadIdx.x;
  int c = tid & 31;          // feature quad 0..31
  int r = tid >> 5;          // edge slice 0..7
  int chunk = (NN + gridDim.x - 1) / gridDim.x;
  int n0 = blockIdx.x * chunk;
  int n1 = min(n0 + chunk, NN);
  float4 bia = ((const float4*)bias)[c];
  float4 ssum = {0,0,0,0}, ssq = {0,0,0,0};
  for (int n = n0; n < n1; ++n){
    int off0 = offs[n], off1 = offs[n + 1];
    float4 acc = {0,0,0,0};
    for (int e = off0 + r; e < off1; e += 8){
      int s = ssorted[e];
      float w = dinv[s];
      float4 h = hl4[(size_t)s * 32 + c];
      acc.x += w * h.x; acc.y += w * h.y; acc.z += w * h.z; acc.w += w * h.w;
    }
    red[tid] = acc;
    __syncthreads();
    if (r < 4){
      float4 o = red[tid + 128];
      acc.x += o.x; acc.y += o.y; acc.z += o.z; acc.w += o.w;
      red[tid] = acc;
    }
    __syncthreads();
    if (r < 2){
      float4 o = red[tid + 64];
      acc.x += o.x; acc.y += o.y; acc.z += o.z; acc.w += o.w;
      red[tid] = acc;
    }
    __syncthreads();
    if (r == 0){
      float4 o = red[tid + 32];
      acc.x += o.x; acc.y += o.y; acc.z += o.z; acc.w += o.w;
      float dv = dinv[n];
      float4 h = hl4[(size_t)n * 32 + c];
      float4 v;
      v.x = (acc.x + dv * h.x) * dv + bia.x;
      v.y = (acc.y + dv * h.y) * dv + bia.y;
      v.z = (acc.z + dv * h.z) * dv + bia.z;
      v.w = (acc.w + dv * h.w) * dv + bia.w;
      agg4[(size_t)n * 32 + c] = v;
      ssum.x += v.x; ssum.y += v.y; ssum.z += v.z; ssum.w += v.w;
      ssq.x += v.x * v.x; ssq.y += v.y * v.y; ssq.z += v.z * v.z; ssq.w += v.w * v.w;
    }
    __syncthreads();
  }
  if (r == 0){
    atomicAdd(&stats[4 * c + 0], ssum.x);
    atomicAdd(&stats[4 * c + 1], ssum.y);
    atomicAdd(&stats[4 * c + 2], ssum.z);
    atomicAdd(&stats[4 * c + 3], ssum.w);
    atomicAdd(&stats[FF + 4 * c + 0], ssq.x);
    atomicAdd(&stats[FF + 4 * c + 1], ssq.y);
    atomicAdd(&stats[FF + 4 * c + 2], ssq.z);
    atomicAdd(&stats[FF + 4 * c + 3], ssq.w);
  }
}

__global__ void k_bnfin(const float* __restrict__ stats, const float* __restrict__ g,
                        const float* __restrict__ b, float* __restrict__ ss){
  int j = threadIdx.x;   // 128
  float mean = stats[j] * (1.0f / NN);
  float var  = stats[FF + j] * (1.0f / NN) - mean * mean;
  float sc = rsqrtf(var + EPSV) * g[j];
  ss[j] = sc;
  ss[FF + j] = b[j] - mean * sc;
}

__global__ void k_bnapply(float4* __restrict__ h, const float* __restrict__ ss, int relu){
  int n4 = NN * FF / 4;
  int stride = gridDim.x * 256;
  for (int i = blockIdx.x * 256 + threadIdx.x; i < n4; i += stride){
    int c = (i & 31) * 4;
    float4 v = h[i];
    float4 sc = *(const float4*)&ss[c];
    float4 sh = *(const float4*)&ss[FF + c];
    v.x = v.x * sc.x + sh.x;
    v.y = v.y * sc.y + sh.y;
    v.z = v.z * sc.z + sh.z;
    v.w = v.w * sc.w + sh.w;
    if (relu){
      v.x = fmaxf(v.x, 0.f); v.y = fmaxf(v.y, 0.f);
      v.z = fmaxf(v.z, 0.f); v.w = fmaxf(v.w, 0.f);
    }
    h[i] = v;
  }
}

// ---------- pooled[v] = sum_{n: mask[v][n]} emb[n]  (mask dtype-adaptive) ----------
__global__ void k_pool(const float* __restrict__ emb, const unsigned char* __restrict__ m8,
                       const int* __restrict__ m32, const int* __restrict__ flag,
                       float* __restrict__ pooled){
  int isb = *flag;
  int tid = blockIdx.x * 256 + threadIdx.x;
  int j = tid & 127;
  int r = tid >> 7;
  int rs = (gridDim.x * 256) >> 7;
  float acc[VV];
  #pragma unroll
  for (int v = 0; v < VV; ++v) acc[v] = 0.f;
  for (; r < NN; r += rs){
    float xv = emb[r * FF + j];
    #pragma unroll
    for (int v = 0; v < VV; ++v){
      int mv = isb ? (int)m8[v * NN + r] : m32[v * NN + r];
      if (mv) acc[v] += xv;
    }
  }
  #pragma unroll
  for (int v = 0; v < VV; ++v) atomicAdd(&pooled[v * FF + j], acc[v]);
}

// ---------- per-VN MLP: F -> 2F (relu, LN) -> F (relu, LN) ----------
__device__ __forceinline__ float blockSum(float x, float* red, int tid){
  red[tid] = x; __syncthreads();
  #pragma unroll
  for (int s = 128; s >= 1; s >>= 1){
    if (tid < s) red[tid] += red[tid + s];
    __syncthreads();
  }
  float r = red[0];
  __syncthreads();
  return r;
}

__launch_bounds__(256)
__global__ void k_vnmlp(const float* __restrict__ pooled, const float* __restrict__ vnin,
                        const float* __restrict__ W1, const float* __restrict__ b1,
                        const float* __restrict__ g1, const float* __restrict__ bb1,
                        const float* __restrict__ W2, const float* __restrict__ b2,
                        const float* __restrict__ g2, const float* __restrict__ bb2,
                        float* __restrict__ vnout){
  int v = blockIdx.x;
  int tid = threadIdx.x;
  __shared__ float tmp_s[FF];
  __shared__ float h1_s[F2];
  __shared__ float red[256];
  if (tid < FF) tmp_s[tid] = pooled[v * FF + tid] + vnin[v * FF + tid];
  __syncthreads();
  const float* W1v = W1 + (size_t)v * FF * F2;
  float acc = b1[v * F2 + tid];
  for (int k = 0; k < FF; ++k) acc += tmp_s[k] * W1v[k * F2 + tid];
  acc = fmaxf(acc, 0.f);
  float sum = blockSum(acc, red, tid);
  float sq  = blockSum(acc * acc, red, tid);
  float mean = sum * (1.f / F2);
  float var  = sq * (1.f / F2) - mean * mean;
  float y = (acc - mean) * rsqrtf(var + EPSV) * g1[v * F2 + tid] + bb1[v * F2 + tid];
  h1_s[tid] = y;
  __syncthreads();
  const float* W2v = W2 + (size_t)v * F2 * FF;
  float h2 = 0.f;
  if (tid < FF){
    float a2 = b2[v * FF + tid];
    for (int k = 0; k < F2; ++k) a2 += h1_s[k] * W2v[k * FF + tid];
    h2 = fmaxf(a2, 0.f);
  }
  float sum2 = blockSum((tid < FF) ? h2 : 0.f, red, tid);
  float sq2  = blockSum((tid < FF) ? h2 * h2 : 0.f, red, tid);
  float mean2 = sum2 * (1.f / FF);
  float var2  = sq2 * (1.f / FF) - mean2 * mean2;
  if (tid < FF)
    vnout[v * FF + tid] = (h2 - mean2) * rsqrtf(var2 + EPSV) * g2[v * FF + tid]
                          + bb2[v * FF + tid];
}

extern "C" void kernel_launch(void* const* d_in, const int* in_sizes, int n_in,
                              void* d_out, int out_size, void* d_ws, size_t ws_size,
                              hipStream_t stream){
  const float* x        = (const float*)d_in[0];
  const int*   ei       = (const int*)d_in[1];
  const unsigned char* vmask8 = (const unsigned char*)d_in[2];
  const int*   vmask32  = (const int*)d_in[2];
  const float* Wc       = (const float*)d_in[3];
  const float* bc       = (const float*)d_in[4];
  const float* bn_g     = (const float*)d_in[5];
  const float* bn_b     = (const float*)d_in[6];
  const float* vn_embed = (const float*)d_in[7];
  const float* mlp_W1   = (const float*)d_in[8];
  const float* mlp_b1   = (const float*)d_in[9];
  const float* ln1_g    = (const float*)d_in[10];
  const float* ln1_b    = (const float*)d_in[11];
  const float* mlp_W2   = (const float*)d_in[12];
  const float* mlp_b2   = (const float*)d_in[13];
  const float* ln2_g    = (const float*)d_in[14];
  const float* ln2_b    = (const float*)d_in[15];
  float* out = (float*)d_out;

  float* bufA    = (float*)d_ws;                    // N*F (hl)
  float* bufB    = bufA + (size_t)NN * FF;          // N*F (agg layer 0)
  int*   ssorted = (int*)(bufB + (size_t)NN * FF);  // E
  int*   offs    = ssorted + EE;                    // N+1
  int*   cursor  = offs + NN + 1;                   // N
  int*   edeg    = cursor + NN;                     // N
  int*   bsum    = edeg + NN;                       // 128
  float* dinv    = (float*)(bsum + 128);            // N
  float* stats   = dinv + NN;                       // 4F (sums | scale/shift)
  float* rowvec  = stats + 4 * FF;                  // F
  float* pooled  = rowvec + FF;                     // V*F
  float* vnA     = pooled + VV * FF;                // V*F
  float* vnB     = vnA + VV * FF;                   // V*F
  int*   mflag   = (int*)(vnB + VV * FF);           // 1

  const int* esrc = ei;
  const int* edst = ei + EE;

  // ----- CSR build (every call; deterministic) -----
  k_edeg_zero<<<idiv(NN, 256), 256, 0, stream>>>(edeg);
  k_deg<<<1024, 256, 0, stream>>>(edst, edeg);
  k_dinv<<<idiv(NN, 256), 256, 0, stream>>>(edeg, dinv);
  k_scanA<<<NB, 1024, 0, stream>>>(edeg, offs, bsum);
  k_scanB<<<1, 128, 0, stream>>>(bsum);
  k_scanC<<<idiv(NN, 256), 256, 0, stream>>>(offs, bsum, cursor);
  k_scatter<<<2048, 256, 0, stream>>>(esrc, edst, cursor, ssorted);

  hipMemsetAsync(mflag, 0, sizeof(int), stream);
  k_maskdetect<<<1, 256, 0, stream>>>(vmask8, mflag);

  const float* vncur = vn_embed;
  const float* embin = x;
  float* vnbufs[2] = {vnA, vnB};

  for (int l = 0; l < LL; ++l){
    float* hl  = bufA;
    float* agg = (l == 0) ? bufB : out;
    const float* Wl = Wc + (size_t)l * FF * FF;

    k_vnrow<<<1, 128, 0, stream>>>(vncur, Wl, rowvec);
    k_matmul<<<2048, 256, 0, stream>>>(embin, Wl, rowvec, hl);

    if (l < LL - 1){
      hipMemsetAsync(pooled, 0, VV * FF * sizeof(float), stream);
      k_pool<<<1024, 256, 0, stream>>>(embin, vmask8, vmask32, mflag, pooled);
    }

    hipMemsetAsync(stats, 0, 2 * FF * sizeof(float), stream);
    k_gather<<<2048, 256, 0, stream>>>((const float4*)hl, dinv, offs, ssorted,
                                       bc + l * FF, (float4*)agg, stats);
    k_bnfin<<<1, 128, 0, stream>>>(stats, bn_g + l * FF, bn_b + l * FF, stats + 2 * FF);
    k_bnapply<<<2048, 256, 0, stream>>>((float4*)agg, stats + 2 * FF, (l < LL - 1) ? 1 : 0);

    if (l < LL - 1){
      k_vnmlp<<<VV, 256, 0, stream>>>(pooled, vncur,
          mlp_W1 + (size_t)l * VV * FF * F2, mlp_b1 + (size_t)l * VV * F2,
          ln1_g + (size_t)l * VV * F2, ln1_b + (size_t)l * VV * F2,
          mlp_W2 + (size_t)l * VV * F2 * FF, mlp_b2 + (size_t)l * VV * FF,
          ln2_g + (size_t)l * VV * FF, ln2_b + (size_t)l * VV * FF,
          vnbufs[l]);
      vncur = vnbufs[l];
      embin = agg;
    }
  }
}

// Round 4
// 1741.497 us; speedup vs baseline: 2.9418x; 1.3383x over previous
//
#include <hip/hip_runtime.h>
#include <hip/hip_bf16.h>
#include <hip/hip_fp16.h>

#define NN 100000
#define EE 3200000
#define FF 128
#define F2 256
#define VV 8
#define LL 3
#define EPSV 1e-5f
#define NB 98   // idiv(NN,1024)

static inline int idiv(int a, int b){ return (a + b - 1) / b; }

// ---------- degree count ----------
__global__ void k_deg(const int* __restrict__ dst, int* __restrict__ edeg){
  int stride = gridDim.x * 256;
  for (int e = blockIdx.x * 256 + threadIdx.x; e < EE; e += stride)
    atomicAdd(&edeg[dst[e]], 1);
}

// ---------- exclusive scan of edeg -> offs (+ dinv) ----------
__global__ void k_scanA(const int* __restrict__ edeg, int* __restrict__ offs,
                        int* __restrict__ bsum, float* __restrict__ dinv){
  __shared__ int s[1024];
  int t = threadIdx.x;
  int i = blockIdx.x * 1024 + t;
  int v = (i < NN) ? edeg[i] : 0;
  if (i < NN) dinv[i] = rsqrtf((float)(v + 1));
  int x = v;
  s[t] = x; __syncthreads();
  for (int d = 1; d < 1024; d <<= 1){
    int y = (t >= d) ? s[t - d] : 0;
    __syncthreads();
    x += y; s[t] = x;
    __syncthreads();
  }
  if (i < NN) offs[i] = x - v;
  if (t == 1023) bsum[blockIdx.x] = x;
}

__global__ void k_scanB(int* __restrict__ bsum){
  __shared__ int s[128];
  int t = threadIdx.x;
  s[t] = (t < NB) ? bsum[t] : 0;
  __syncthreads();
  if (t == 0){
    int run = 0;
    for (int k = 0; k < NB; ++k){ int tmp = s[k]; s[k] = run; run += tmp; }
  }
  __syncthreads();
  if (t < NB) bsum[t] = s[t];
}

__global__ void k_scanC(int* __restrict__ offs, const int* __restrict__ bsum,
                        int* __restrict__ cursor){
  int i = blockIdx.x * 256 + threadIdx.x;
  if (i < NN){
    int o = offs[i] + bsum[i >> 10];
    offs[i] = o;
    cursor[i] = o;
  }
  if (i == 0) offs[NN] = EE;
}

// ---------- counting-sort scatter ----------
__global__ void k_scatter(const int* __restrict__ src, const int* __restrict__ dst,
                          int* __restrict__ cursor, int* __restrict__ ssorted){
  int stride = gridDim.x * 256;
  for (int e = blockIdx.x * 256 + threadIdx.x; e < EE; e += stride){
    int d = dst[e];
    int pos = atomicAdd(&cursor[d], 1);
    ssorted[pos] = src[e];
  }
}

// ---------- mask dtype detect: 1 = bool(1B), 0 = int32 ----------
__global__ void k_maskdetect(const unsigned char* __restrict__ m, int* __restrict__ flag){
  int any = 0;
  for (int t = threadIdx.x; t < 4096; t += 256)
    if ((t & 3) && m[t]) any = 1;
  if (any) atomicOr(flag, 1);
}

// ---------- hlb[n] = fp16( (emb[n]@W + (sum_v vn)@W) * dinv[n] ) ----------
__launch_bounds__(256)
__global__ void k_matmul(const float* __restrict__ in, const float* __restrict__ W,
                         const float* __restrict__ vn, const float* __restrict__ dinv,
                         uint2* __restrict__ hlb){
  __shared__ float Ws[FF * FF];     // 64 KB
  __shared__ float As[8 * FF];      // 4 KB
  __shared__ float vs[FF];
  __shared__ float rv[FF];
  int tid = threadIdx.x;
  for (int t = tid; t < FF * FF; t += 256) Ws[t] = W[t];
  if (tid < FF){
    float s = 0.f;
    for (int v = 0; v < VV; ++v) s += vn[v * FF + tid];
    vs[tid] = s;
  }
  __syncthreads();
  if (tid < FF){
    float a = 0.f;
    for (int k = 0; k < FF; ++k) a += vs[k] * Ws[k * FF + tid];
    rv[tid] = a;
  }
  __syncthreads();
  int row = tid >> 5;               // 0..7
  int col = (tid & 31) * 4;         // 0..124
  float4 rvv = *(const float4*)&rv[col];
  for (int base = blockIdx.x * 8; base < NN; base += gridDim.x * 8){
    for (int t = tid; t < 8 * FF; t += 256)
      As[t] = in[(base + (t >> 7)) * FF + (t & 127)];
    __syncthreads();
    float4 acc = rvv;
    #pragma unroll 8
    for (int k = 0; k < FF; ++k){
      float a = As[row * FF + k];
      float4 wv = *(const float4*)&Ws[k * FF + col];
      acc.x += a * wv.x; acc.y += a * wv.y; acc.z += a * wv.z; acc.w += a * wv.w;
    }
    float d = dinv[base + row];
    __half2 h01 = __floats2half2_rn(acc.x * d, acc.y * d);
    __half2 h23 = __floats2half2_rn(acc.z * d, acc.w * d);
    uint2 pk;
    pk.x = *reinterpret_cast<unsigned int*>(&h01);
    pk.y = *reinterpret_cast<unsigned int*>(&h23);
    hlb[(size_t)(base + row) * 32 + (tid & 31)] = pk;
    __syncthreads();
  }
}

// ---------- wave-per-node CSR gather + BN stats ----------
__launch_bounds__(256)
__global__ void k_gather(const unsigned int* __restrict__ hlb, const float* __restrict__ dinv,
                         const int* __restrict__ offs, const int* __restrict__ ssorted,
                         float2* __restrict__ agg2, float* __restrict__ stats){
  int tid = threadIdx.x;
  int lane = tid & 63;
  int wid = (blockIdx.x * 256 + tid) >> 6;
  int nw = (gridDim.x * 256) >> 6;
  float s0 = 0.f, s1 = 0.f, q0 = 0.f, q1 = 0.f;
  for (int n = wid; n < NN; n += nw){
    int off0 = offs[n], off1 = offs[n + 1];
    unsigned int ps = hlb[(size_t)n * 64 + lane];   // self term (prescaled)
    float2 acc = __half22float2(*reinterpret_cast<__half2*>(&ps));
    #pragma unroll 4
    for (int e = off0; e < off1; ++e){
      unsigned int p = hlb[(size_t)ssorted[e] * 64 + lane];
      float2 f = __half22float2(*reinterpret_cast<__half2*>(&p));
      acc.x += f.x; acc.y += f.y;
    }
    float dv = dinv[n];
    float v0 = acc.x * dv, v1 = acc.y * dv;
    agg2[(size_t)n * 64 + lane] = make_float2(v0, v1);
    s0 += v0; s1 += v1; q0 += v0 * v0; q1 += v1 * v1;
  }
  __shared__ float4 red[256];
  red[tid] = make_float4(s0, s1, q0, q1);
  __syncthreads();
  if (tid < 64){
    float4 a = red[tid], b = red[tid + 64], c = red[tid + 128], d = red[tid + 192];
    a.x += b.x + c.x + d.x; a.y += b.y + c.y + d.y;
    a.z += b.z + c.z + d.z; a.w += b.w + c.w + d.w;
    atomicAdd(&stats[2 * tid], a.x);
    atomicAdd(&stats[2 * tid + 1], a.y);
    atomicAdd(&stats[FF + 2 * tid], a.z);
    atomicAdd(&stats[FF + 2 * tid + 1], a.w);
  }
}

// ---------- BN finalize + apply (+relu) ----------
__launch_bounds__(256)
__global__ void k_bnapply(float4* __restrict__ h, const float* __restrict__ stats,
                          const float* __restrict__ g, const float* __restrict__ b,
                          int relu){
  __shared__ float ss[2 * FF];
  int tid = threadIdx.x;
  if (tid < FF){
    float mean = stats[tid] * (1.0f / NN);
    float var  = stats[FF + tid] * (1.0f / NN) - mean * mean;
    float sc = rsqrtf(var + EPSV) * g[tid];
    ss[tid] = sc;
    ss[FF + tid] = b[tid] - mean * sc;
  }
  __syncthreads();
  int n4 = NN * FF / 4;
  int stride = gridDim.x * 256;
  for (int i = blockIdx.x * 256 + tid; i < n4; i += stride){
    int c = (i & 31) * 4;
    float4 v = h[i];
    float4 sc = *(const float4*)&ss[c];
    float4 sh = *(const float4*)&ss[FF + c];
    v.x = v.x * sc.x + sh.x;
    v.y = v.y * sc.y + sh.y;
    v.z = v.z * sc.z + sh.z;
    v.w = v.w * sc.w + sh.w;
    if (relu){
      v.x = fmaxf(v.x, 0.f); v.y = fmaxf(v.y, 0.f);
      v.z = fmaxf(v.z, 0.f); v.w = fmaxf(v.w, 0.f);
    }
    h[i] = v;
  }
}

// ---------- pooled[v] = sum_{n: mask[v][n]} emb[n] ----------
__global__ void k_pool(const float* __restrict__ emb, const unsigned char* __restrict__ m8,
                       const int* __restrict__ m32, const int* __restrict__ flag,
                       float* __restrict__ pooled){
  int isb = *flag;
  int tid = blockIdx.x * 256 + threadIdx.x;
  int j = tid & 127;
  int r = tid >> 7;
  int rs = (gridDim.x * 256) >> 7;
  float acc[VV];
  #pragma unroll
  for (int v = 0; v < VV; ++v) acc[v] = 0.f;
  for (; r < NN; r += rs){
    float xv = emb[r * FF + j];
    #pragma unroll
    for (int v = 0; v < VV; ++v){
      int mv = isb ? (int)m8[v * NN + r] : m32[v * NN + r];
      if (mv) acc[v] += xv;
    }
  }
  #pragma unroll
  for (int v = 0; v < VV; ++v) atomicAdd(&pooled[v * FF + j], acc[v]);
}

// ---------- per-VN MLP ----------
__device__ __forceinline__ float blockSum(float x, float* red, int tid){
  red[tid] = x; __syncthreads();
  #pragma unroll
  for (int s = 128; s >= 1; s >>= 1){
    if (tid < s) red[tid] += red[tid + s];
    __syncthreads();
  }
  float r = red[0];
  __syncthreads();
  return r;
}

__launch_bounds__(256)
__global__ void k_vnmlp(const float* __restrict__ pooled, const float* __restrict__ vnin,
                        const float* __restrict__ W1, const float* __restrict__ b1,
                        const float* __restrict__ g1, const float* __restrict__ bb1,
                        const float* __restrict__ W2, const float* __restrict__ b2,
                        const float* __restrict__ g2, const float* __restrict__ bb2,
                        float* __restrict__ vnout){
  int v = blockIdx.x;
  int tid = threadIdx.x;
  __shared__ float tmp_s[FF];
  __shared__ float h1_s[F2];
  __shared__ float red[256];
  if (tid < FF) tmp_s[tid] = pooled[v * FF + tid] + vnin[v * FF + tid];
  __syncthreads();
  const float* W1v = W1 + (size_t)v * FF * F2;
  float acc = b1[v * F2 + tid];
  for (int k = 0; k < FF; ++k) acc += tmp_s[k] * W1v[k * F2 + tid];
  acc = fmaxf(acc, 0.f);
  float sum = blockSum(acc, red, tid);
  float sq  = blockSum(acc * acc, red, tid);
  float mean = sum * (1.f / F2);
  float var  = sq * (1.f / F2) - mean * mean;
  float y = (acc - mean) * rsqrtf(var + EPSV) * g1[v * F2 + tid] + bb1[v * F2 + tid];
  h1_s[tid] = y;
  __syncthreads();
  const float* W2v = W2 + (size_t)v * F2 * FF;
  float h2 = 0.f;
  if (tid < FF){
    float a2 = b2[v * FF + tid];
    for (int k = 0; k < F2; ++k) a2 += h1_s[k] * W2v[k * FF + tid];
    h2 = fmaxf(a2, 0.f);
  }
  float sum2 = blockSum((tid < FF) ? h2 : 0.f, red, tid);
  float sq2  = blockSum((tid < FF) ? h2 * h2 : 0.f, red, tid);
  float mean2 = sum2 * (1.f / FF);
  float var2  = sq2 * (1.f / FF) - mean2 * mean2;
  if (tid < FF)
    vnout[v * FF + tid] = (h2 - mean2) * rsqrtf(var2 + EPSV) * g2[v * FF + tid]
                          + bb2[v * FF + tid];
}

extern "C" void kernel_launch(void* const* d_in, const int* in_sizes, int n_in,
                              void* d_out, int out_size, void* d_ws, size_t ws_size,
                              hipStream_t stream){
  const float* x        = (const float*)d_in[0];
  const int*   ei       = (const int*)d_in[1];
  const unsigned char* vmask8 = (const unsigned char*)d_in[2];
  const int*   vmask32  = (const int*)d_in[2];
  const float* Wc       = (const float*)d_in[3];
  const float* bn_g     = (const float*)d_in[5];
  const float* bn_b     = (const float*)d_in[6];
  const float* vn_embed = (const float*)d_in[7];
  const float* mlp_W1   = (const float*)d_in[8];
  const float* mlp_b1   = (const float*)d_in[9];
  const float* ln1_g    = (const float*)d_in[10];
  const float* ln1_b    = (const float*)d_in[11];
  const float* mlp_W2   = (const float*)d_in[12];
  const float* mlp_b2   = (const float*)d_in[13];
  const float* ln2_g    = (const float*)d_in[14];
  const float* ln2_b    = (const float*)d_in[15];
  float* out = (float*)d_out;

  unsigned int* hlb = (unsigned int*)d_ws;               // N*64 uint (fp16 x2) = 25.6MB
  float* bufB    = (float*)(hlb + (size_t)NN * 64);      // N*F f32 (layer-0 out)
  int*   ssorted = (int*)(bufB + (size_t)NN * FF);       // E
  int*   offs    = ssorted + EE;                         // N+1
  int*   cursor  = offs + NN + 1;                        // N
  int*   edeg    = cursor + NN;                          // N
  int*   bsum    = edeg + NN;                            // 128
  float* dinv    = (float*)(bsum + 128);                 // N
  float* stats   = dinv + NN;                            // 2F
  float* pooled  = stats + 2 * FF;                       // V*F
  float* vnA     = pooled + VV * FF;                     // V*F
  float* vnB     = vnA + VV * FF;                        // V*F
  int*   mflag   = (int*)(vnB + VV * FF);                // 1

  const int* esrc = ei;
  const int* edst = ei + EE;

  // ----- CSR build -----
  hipMemsetAsync(edeg, 0, NN * sizeof(int), stream);
  k_deg<<<1024, 256, 0, stream>>>(edst, edeg);
  k_scanA<<<NB, 1024, 0, stream>>>(edeg, offs, bsum, dinv);
  k_scanB<<<1, 128, 0, stream>>>(bsum);
  k_scanC<<<idiv(NN, 256), 256, 0, stream>>>(offs, bsum, cursor);
  k_scatter<<<2048, 256, 0, stream>>>(esrc, edst, cursor, ssorted);

  hipMemsetAsync(mflag, 0, sizeof(int), stream);
  k_maskdetect<<<1, 256, 0, stream>>>(vmask8, mflag);

  const float* vncur = vn_embed;
  const float* embin = x;
  float* vnbufs[2] = {vnA, vnB};

  for (int l = 0; l < LL; ++l){
    float* agg = (l == 0) ? bufB : out;
    const float* Wl = Wc + (size_t)l * FF * FF;

    k_matmul<<<2048, 256, 0, stream>>>(embin, Wl, vncur, dinv, (uint2*)hlb);

    if (l < LL - 1){
      hipMemsetAsync(pooled, 0, VV * FF * sizeof(float), stream);
      k_pool<<<1024, 256, 0, stream>>>(embin, vmask8, vmask32, mflag, pooled);
    }

    hipMemsetAsync(stats, 0, 2 * FF * sizeof(float), stream);
    k_gather<<<2048, 256, 0, stream>>>(hlb, dinv, offs, ssorted, (float2*)agg, stats);
    k_bnapply<<<1024, 256, 0, stream>>>((float4*)agg, stats,
                                        bn_g + l * FF, bn_b + l * FF, (l < LL - 1) ? 1 : 0);

    if (l < LL - 1){
      k_vnmlp<<<VV, 256, 0, stream>>>(pooled, vncur,
          mlp_W1 + (size_t)l * VV * FF * F2, mlp_b1 + (size_t)l * VV * F2,
          ln1_g + (size_t)l * VV * F2, ln1_b + (size_t)l * VV * F2,
          mlp_W2 + (size_t)l * VV * F2 * FF, mlp_b2 + (size_t)l * VV * FF,
          ln2_g + (size_t)l * VV * FF, ln2_b + (size_t)l * VV * FF,
          vnbufs[l]);
      vncur = vnbufs[l];
      embin = agg;
    }
  }
}